// Round 3
// baseline (23116.072 us; speedup 1.0000x reference)
//
#include <hip/hip_runtime.h>

typedef short bf16x8 __attribute__((ext_vector_type(8)));
typedef float f32x4 __attribute__((ext_vector_type(4)));

static constexpr int kT  = 256;
static constexpr int kNU = 64;
static constexpr int kNX = 128;
static constexpr int kNY = 16;
static constexpr int kBT = 16;   // batch rows per block

// packed weight region sizes (elements)
static constexpr int kW1P = 64 * 6 * 64 * 8;   // 196608
static constexpr int kW2P = 8 * 32 * 64 * 8;   // 131072
static constexpr int kCP  = 4 * 64 * 8;        // 2048
static constexpr int kDP  = 2 * 64 * 8;        // 1024
static constexpr int kPackTotal = kW1P + kW2P + kCP + kDP; // 330752

__device__ __forceinline__ unsigned short f2bf(float f) {
  union { float f; unsigned int u; } v; v.f = f;
  unsigned int r = v.u + 0x7fffu + ((v.u >> 16) & 1u);   // RNE to bf16
  return (unsigned short)(r >> 16);
}

// Pack W1/W2/C/D (fp32) into bf16 MFMA B-fragment order:
// frag index (n, ks, lane, j) holds W[16n + (lane&15)][32ks + 8*(lane>>4) + j]
__global__ __launch_bounds__(256)
void prepack_kernel(const float* __restrict__ W1, const float* __restrict__ W2,
                    const float* __restrict__ C, const float* __restrict__ D,
                    unsigned short* __restrict__ wp) {
  int i = blockIdx.x * 256 + threadIdx.x;
  if (i >= kPackTotal) return;
  float v;
  if (i < kW1P) {
    int j = i & 7, l = (i >> 3) & 63, t = i >> 9;
    int ks = t % 6, n = t / 6;
    v = W1[(16 * n + (l & 15)) * 192 + 32 * ks + 8 * (l >> 4) + j];
  } else if (i < kW1P + kW2P) {
    int k = i - kW1P;
    int j = k & 7, l = (k >> 3) & 63, t = k >> 9;
    int ks = t & 31, n = t >> 5;
    v = W2[(16 * n + (l & 15)) * 1024 + 32 * ks + 8 * (l >> 4) + j];
  } else if (i < kW1P + kW2P + kCP) {
    int k = i - (kW1P + kW2P);
    int j = k & 7, l = (k >> 3) & 63, ks = k >> 9;
    v = C[(l & 15) * 128 + 32 * ks + 8 * (l >> 4) + j];
  } else {
    int k = i - (kW1P + kW2P + kCP);
    int j = k & 7, l = (k >> 3) & 63, ks = k >> 9;
    v = D[(l & 15) * 64 + 32 * ks + 8 * (l >> 4) + j];
  }
  wp[i] = f2bf(v);
}

// RK45 stage-combination coefficients (dt folded in), row e = coeffs for z of stage e+2
__constant__ float CTc[5][5] = {
  {(float)(0.01 / 4.0), 0.f, 0.f, 0.f, 0.f},
  {(float)(0.01 * 3.0 / 32.0), (float)(0.01 * 9.0 / 32.0), 0.f, 0.f, 0.f},
  {(float)(0.01 * 1932.0 / 2197.0), (float)(-0.01 * 7200.0 / 2197.0), (float)(0.01 * 7296.0 / 2197.0), 0.f, 0.f},
  {(float)(0.01 * 439.0 / 216.0), (float)(-0.01 * 8.0), (float)(0.01 * 3680.0 / 513.0), (float)(-0.01 * 845.0 / 4104.0), 0.f},
  {(float)(-0.01 * 8.0 / 27.0), (float)(0.01 * 2.0), (float)(-0.01 * 3544.0 / 2565.0), (float)(0.01 * 1859.0 / 4104.0), (float)(-0.01 * 11.0 / 40.0)}
};

// tanh(x) = 1 - 2/(exp2(2x*log2 e)+1); v_rcp_f32 is plenty for bf16-level accuracy.
__device__ __forceinline__ float tanh_fast(float x) {
  float t = exp2f(x * 2.8853900817779268f);
  return 1.0f - 2.0f * __builtin_amdgcn_rcpf(t + 1.0f);
}

// One block = 16 batch rows, 16 waves (4/SIMD). Whole T-loop inside the kernel.
// matmul1: 64 NH-tiles split 4 per wave. matmul2: split-K (2 halves of 512),
// 8 column-tiles x 2 K-halves = 16 waves; K-half-1 partials reduced via LDS.
__global__ __launch_bounds__(1024, 4)
void rk45_kernel(const float* __restrict__ u, const float* __restrict__ x0,
                 const float* __restrict__ b1g, const float* __restrict__ b2g,
                 const unsigned short* __restrict__ wp,
                 float* __restrict__ Xout, float* __restrict__ Yout) {
  __shared__ unsigned short zs[16][232];   // z = [x | u] bf16 (cols 0..127 x, 128..191 u)
  __shared__ unsigned short hs[16][1048];  // h bf16 (16 x 1024), XOR-swizzled cols
  __shared__ float ps[16][132];            // split-K partial sums (padded stride)

  const int tid  = threadIdx.x;
  const int lane = tid & 63;
  const int w    = tid >> 6;     // wave 0..15
  const int r16  = lane & 15;
  const int g    = lane >> 4;    // 0..3
  const int nc   = w & 7;        // matmul2 column-tile
  const int kh   = w >> 3;       // matmul2 K-half
  const int b0   = blockIdx.x * kBT;
  const int colw = 16 * nc + r16;

  const bf16x8* W1P = (const bf16x8*)wp;
  const bf16x8* W2P = (const bf16x8*)(wp + kW1P);
  const bf16x8* CP  = (const bf16x8*)(wp + kW1P + kW2P);
  const bf16x8* DP  = (const bf16x8*)(wp + kW1P + kW2P + kCP);

  // bias registers
  float b1r[4];
  #pragma unroll
  for (int nt = 0; nt < 4; ++nt)
    b1r[nt] = b1g[64 * w + 16 * nt + r16];
  const float b2reg = b2g[colw];

  // state registers (meaningful in waves 0..7; mapping row=4g+q, col=colw)
  float xreg[4];
  #pragma unroll
  for (int q = 0; q < 4; ++q)
    xreg[q] = x0[(b0 + 4 * g + q) * kNX + colw];

  if (w < 8) {
    #pragma unroll
    for (int q = 0; q < 4; ++q) {
      Xout[((b0 + 4 * g + q) * kT + 0) * kNX + colw] = xreg[q];   // X[0] = x0
      zs[4 * g + q][colw] = f2bf(xreg[q]);
    }
  }
  // u_0 commit (1 element per thread)
  {
    int row = tid >> 6, col = tid & 63;
    zs[row][kNX + col] = f2bf(u[((b0 + row) * kT + 0) * kNU + col]);
  }
  // u prefetch (waves 8..15 own the steady-state u pipeline)
  const int urow = (tid >> 5) & 15, ucol = (tid & 31) * 2;
  float2 ureg = {0.f, 0.f};
  if (w >= 8)
    ureg = *(const float2*)&u[((b0 + urow) * kT + 1) * kNU + ucol];
  __syncthreads();

  f32x4 k1r = {0,0,0,0}, k2r = {0,0,0,0}, k3r = {0,0,0,0}, k4r = {0,0,0,0}, k5r = {0,0,0,0};

  const float D1 = (float)(0.01 * 16.0 / 135.0);
  const float D3 = (float)(0.01 * 6656.0 / 12825.0);
  const float D4 = (float)(0.01 * 28561.0 / 56430.0);
  const float D5 = (float)(-0.01 * 9.0 / 50.0);
  const float D6 = (float)(0.01 * 2.0 / 55.0);

  #pragma unroll 1
  for (int t = 0; t < kT; ++t) {
    #pragma unroll 1
    for (int e = 0; e < 6; ++e) {
      // ---- matmul1: h = tanh(z @ W1^T + b1); wave w owns NH tiles [4w, 4w+4)
      bf16x8 za[6];
      #pragma unroll
      for (int ks = 0; ks < 6; ++ks)
        za[ks] = *(const bf16x8*)&zs[r16][8 * g + 32 * ks];

      #pragma unroll
      for (int nt = 0; nt < 4; ++nt) {
        int n = 4 * w + nt;
        const bf16x8* w1p = W1P + n * 6 * 64 + lane;
        f32x4 aa = {0,0,0,0}, ab = {0,0,0,0};
        #pragma unroll
        for (int ks = 0; ks < 6; ks += 2) {
          aa = __builtin_amdgcn_mfma_f32_16x16x32_bf16(za[ks],     w1p[ks * 64],       aa, 0, 0, 0);
          ab = __builtin_amdgcn_mfma_f32_16x16x32_bf16(za[ks + 1], w1p[(ks + 1) * 64], ab, 0, 0, 0);
        }
        float bias = b1r[nt];
        #pragma unroll
        for (int q = 0; q < 4; ++q) {
          float hv = tanh_fast(aa[q] + ab[q] + bias);
          int row = 4 * g + q;
          hs[row][(16 * n + r16) ^ ((row & 7) << 3)] = f2bf(hv);
        }
      }
      if (e == 0 && w == 0) {
        // y_t = x C^T + u D^T, reuses z fragments (z k 0..127 = x -> C, 128..191 = u -> D)
        f32x4 ay = {0,0,0,0};
        #pragma unroll
        for (int ks = 0; ks < 4; ++ks)
          ay = __builtin_amdgcn_mfma_f32_16x16x32_bf16(za[ks], CP[ks * 64 + lane], ay, 0, 0, 0);
        ay = __builtin_amdgcn_mfma_f32_16x16x32_bf16(za[4], DP[lane],      ay, 0, 0, 0);
        ay = __builtin_amdgcn_mfma_f32_16x16x32_bf16(za[5], DP[64 + lane], ay, 0, 0, 0);
        #pragma unroll
        for (int q = 0; q < 4; ++q)
          Yout[((b0 + 4 * g + q) * kT + t) * kNY + r16] = ay[q];
      }
      __syncthreads();

      // ---- matmul2: k = h @ W2^T + b2; wave (nc, kh) does cols [16nc,16nc+16), K [512kh, 512kh+512)
      f32x4 ka = {0,0,0,0}, kb = {0,0,0,0};
      const bf16x8* w2p = W2P + nc * 32 * 64 + 16 * kh * 64 + lane;
      const int swz = (r16 & 7) << 3;
      #pragma unroll
      for (int ks = 0; ks < 16; ks += 2) {
        int c0 = (512 * kh + 32 * ks + 8 * g) ^ swz;
        int c1 = (512 * kh + 32 * (ks + 1) + 8 * g) ^ swz;
        bf16x8 h0 = *(const bf16x8*)&hs[r16][c0];
        bf16x8 h1 = *(const bf16x8*)&hs[r16][c1];
        ka = __builtin_amdgcn_mfma_f32_16x16x32_bf16(h0, w2p[ks * 64],       ka, 0, 0, 0);
        kb = __builtin_amdgcn_mfma_f32_16x16x32_bf16(h1, w2p[(ks + 1) * 64], kb, 0, 0, 0);
      }
      f32x4 kv = ka + kb;

      if (kh == 1) {
        #pragma unroll
        for (int q = 0; q < 4; ++q) ps[4 * g + q][colw] = kv[q];
      }
      __syncthreads();

      if (w < 8) {
        #pragma unroll
        for (int q = 0; q < 4; ++q) kv[q] += ps[4 * g + q][colw] + b2reg;

        if      (e == 0) k1r = kv;
        else if (e == 1) k2r = kv;
        else if (e == 2) k3r = kv;
        else if (e == 3) k4r = kv;
        else if (e == 4) k5r = kv;

        if (e < 5) {
          float c1 = CTc[e][0], c2 = CTc[e][1], c3 = CTc[e][2], c4 = CTc[e][3], c5 = CTc[e][4];
          #pragma unroll
          for (int q = 0; q < 4; ++q) {
            float xt = xreg[q] + c1 * k1r[q] + c2 * k2r[q] + c3 * k3r[q] + c4 * k4r[q] + c5 * k5r[q];
            zs[4 * g + q][colw] = f2bf(xt);
          }
        } else {
          #pragma unroll
          for (int q = 0; q < 4; ++q) {
            float xn = xreg[q] + (D1 * k1r[q] + D3 * k3r[q] + D4 * k4r[q] + D5 * k5r[q] + D6 * kv[q]);
            xreg[q] = xn;
            zs[4 * g + q][colw] = f2bf(xn);
            if (t + 1 < kT)
              Xout[((b0 + 4 * g + q) * kT + (t + 1)) * kNX + colw] = xn;
          }
        }
      } else if (e == 5) {
        // waves 8..15: commit u_{t+1}, prefetch u_{t+2}
        if (t + 1 < kT) {
          zs[urow][kNX + ucol]     = f2bf(ureg.x);
          zs[urow][kNX + ucol + 1] = f2bf(ureg.y);
        }
        if (t + 2 < kT)
          ureg = *(const float2*)&u[((b0 + urow) * kT + (t + 2)) * kNU + ucol];
      }
      __syncthreads();
    }
  }
}

extern "C" void kernel_launch(void* const* d_in, const int* in_sizes, int n_in,
                              void* d_out, int out_size, void* d_ws, size_t ws_size,
                              hipStream_t stream) {
  const float* u  = (const float*)d_in[0];
  const float* x0 = (const float*)d_in[1];
  const float* W1 = (const float*)d_in[2];
  const float* b1 = (const float*)d_in[3];
  const float* W2 = (const float*)d_in[4];
  const float* b2 = (const float*)d_in[5];
  const float* C  = (const float*)d_in[6];
  const float* D  = (const float*)d_in[7];

  unsigned short* wp = (unsigned short*)d_ws;
  float* Xout = (float*)d_out;
  float* Yout = Xout + (size_t)512 * 256 * 128;

  hipLaunchKernelGGL(prepack_kernel, dim3((kPackTotal + 255) / 256), dim3(256), 0, stream,
                     W1, W2, C, D, wp);
  hipLaunchKernelGGL(rk45_kernel, dim3(32), dim3(1024), 0, stream,
                     u, x0, b1, b2, (const unsigned short*)wp, Xout, Yout);
}

// Round 4
// 16308.609 us; speedup vs baseline: 1.4174x; 1.4174x over previous
//
#include <hip/hip_runtime.h>

typedef short bf16x8 __attribute__((ext_vector_type(8)));
typedef float f32x4 __attribute__((ext_vector_type(4)));

static constexpr int kT  = 256;
static constexpr int kNU = 64;
static constexpr int kNX = 128;
static constexpr int kNY = 16;
static constexpr int kBT = 16;   // batch rows per block

// packed weight region sizes (elements)
static constexpr int kW1P = 64 * 6 * 64 * 8;   // 196608
static constexpr int kW2P = 8 * 32 * 64 * 8;   // 131072
static constexpr int kCP  = 4 * 64 * 8;        // 2048
static constexpr int kDP  = 2 * 64 * 8;        // 1024
static constexpr int kPackTotal = kW1P + kW2P + kCP + kDP; // 330752

__device__ __forceinline__ unsigned short f2bf(float f) {
  union { float f; unsigned int u; } v; v.f = f;
  unsigned int r = v.u + 0x7fffu + ((v.u >> 16) & 1u);   // RNE to bf16
  return (unsigned short)(r >> 16);
}

// Pack W1/W2/C/D (fp32) into bf16 MFMA B-fragment order:
// frag index (n, ks, lane, j) holds W[16n + (lane&15)][32ks + 8*(lane>>4) + j]
__global__ __launch_bounds__(256)
void prepack_kernel(const float* __restrict__ W1, const float* __restrict__ W2,
                    const float* __restrict__ C, const float* __restrict__ D,
                    unsigned short* __restrict__ wp) {
  int i = blockIdx.x * 256 + threadIdx.x;
  if (i >= kPackTotal) return;
  float v;
  if (i < kW1P) {
    int j = i & 7, l = (i >> 3) & 63, t = i >> 9;
    int ks = t % 6, n = t / 6;
    v = W1[(16 * n + (l & 15)) * 192 + 32 * ks + 8 * (l >> 4) + j];
  } else if (i < kW1P + kW2P) {
    int k = i - kW1P;
    int j = k & 7, l = (k >> 3) & 63, t = k >> 9;
    int ks = t & 31, n = t >> 5;
    v = W2[(16 * n + (l & 15)) * 1024 + 32 * ks + 8 * (l >> 4) + j];
  } else if (i < kW1P + kW2P + kCP) {
    int k = i - (kW1P + kW2P);
    int j = k & 7, l = (k >> 3) & 63, ks = k >> 9;
    v = C[(l & 15) * 128 + 32 * ks + 8 * (l >> 4) + j];
  } else {
    int k = i - (kW1P + kW2P + kCP);
    int j = k & 7, l = (k >> 3) & 63, ks = k >> 9;
    v = D[(l & 15) * 64 + 32 * ks + 8 * (l >> 4) + j];
  }
  wp[i] = f2bf(v);
}

// RK45 stage-combination coefficients (dt folded in), row e = coeffs for z of stage e+2
__constant__ float CTc[5][5] = {
  {(float)(0.01 / 4.0), 0.f, 0.f, 0.f, 0.f},
  {(float)(0.01 * 3.0 / 32.0), (float)(0.01 * 9.0 / 32.0), 0.f, 0.f, 0.f},
  {(float)(0.01 * 1932.0 / 2197.0), (float)(-0.01 * 7200.0 / 2197.0), (float)(0.01 * 7296.0 / 2197.0), 0.f, 0.f},
  {(float)(0.01 * 439.0 / 216.0), (float)(-0.01 * 8.0), (float)(0.01 * 3680.0 / 513.0), (float)(-0.01 * 845.0 / 4104.0), 0.f},
  {(float)(-0.01 * 8.0 / 27.0), (float)(0.01 * 2.0), (float)(-0.01 * 3544.0 / 2565.0), (float)(0.01 * 1859.0 / 4104.0), (float)(-0.01 * 11.0 / 40.0)}
};

// tanh(x) = 1 - 2/(exp2(2x*log2 e)+1); v_rcp_f32 is plenty for bf16-level accuracy.
__device__ __forceinline__ float tanh_fast(float x) {
  float t = exp2f(x * 2.8853900817779268f);
  return 1.0f - 2.0f * __builtin_amdgcn_rcpf(t + 1.0f);
}

// One block = 16 batch rows, 8 waves. Whole T-loop runs inside the kernel.
__global__ __launch_bounds__(512, 2)
void rk45_kernel(const float* __restrict__ u, const float* __restrict__ x0,
                 const float* __restrict__ b1g, const float* __restrict__ b2g,
                 const unsigned short* __restrict__ wp,
                 float* __restrict__ Xout, float* __restrict__ Yout) {
  __shared__ unsigned short zs[16][232];   // z = [x | u] bf16 (cols 0..127 x, 128..191 u)
  __shared__ unsigned short hs[16][1048];  // h bf16 (16 x 1024)
  __shared__ float xs[16][132];            // master state fp32

  const int tid  = threadIdx.x;
  const int lane = tid & 63;
  const int w    = tid >> 6;     // wave 0..7
  const int r16  = lane & 15;
  const int g    = lane >> 4;    // 0..3
  const int b0   = blockIdx.x * kBT;
  const int colw = 16 * w + r16; // this lane's NX column in matmul2 mapping

  const bf16x8* W1P = (const bf16x8*)wp;
  const bf16x8* W2P = (const bf16x8*)(wp + kW1P);
  const bf16x8* CP  = (const bf16x8*)(wp + kW1P + kW2P);
  const bf16x8* DP  = (const bf16x8*)(wp + kW1P + kW2P + kCP);

  // bias registers (small, safe)
  float b1r[8];
  #pragma unroll
  for (int nt = 0; nt < 8; ++nt)
    b1r[nt] = b1g[128 * w + 16 * nt + r16];
  const float b2reg = b2g[colw];

  float xreg[4];
  f32x4 k1r = {0,0,0,0}, k2r = {0,0,0,0}, k3r = {0,0,0,0}, k4r = {0,0,0,0}, k5r = {0,0,0,0};

  #pragma unroll
  for (int q = 0; q < 4; ++q) {
    int row = 4 * g + q;
    float xv = x0[(b0 + row) * kNX + colw];
    xreg[q] = xv;
    xs[row][colw] = xv;
    zs[row][colw] = f2bf(xv);
  }

  // u prefetch (one step ahead)
  const int urow = tid >> 5, ucol = (tid & 31) * 2;
  float2 ureg = *(const float2*)&u[((b0 + urow) * kT + 0) * kNU + ucol];
  __syncthreads();

  const float D1 = (float)(0.01 * 16.0 / 135.0);
  const float D3 = (float)(0.01 * 6656.0 / 12825.0);
  const float D4 = (float)(0.01 * 28561.0 / 56430.0);
  const float D5 = (float)(-0.01 * 9.0 / 50.0);
  const float D6 = (float)(0.01 * 2.0 / 55.0);

  #pragma unroll 1
  for (int t = 0; t < kT; ++t) {
    // ---- stage A: write X[t] = x_t (coalesced via xs), commit u_t, prefetch u_{t+1}
    {
      int base = tid * 4, row = base >> 7, col = base & 127;
      float4 xv = *(const float4*)&xs[row][col];
      *(float4*)&Xout[((b0 + row) * kT + t) * kNX + col] = xv;
      zs[urow][kNX + ucol]     = f2bf(ureg.x);
      zs[urow][kNX + ucol + 1] = f2bf(ureg.y);
      if (t + 1 < kT)
        ureg = *(const float2*)&u[((b0 + urow) * kT + (t + 1)) * kNU + ucol];
    }
    __syncthreads();

    #pragma unroll 1
    for (int e = 0; e < 6; ++e) {
      // ---- matmul1: h = tanh(z @ W1^T + b1); wave w owns NH slice [128w, 128w+128)
      bf16x8 za[6];
      #pragma unroll
      for (int ks = 0; ks < 6; ++ks)
        za[ks] = *(const bf16x8*)&zs[r16][8 * g + 32 * ks];

      // fully unrolled: 48 independent W1 loads, scheduler hoists them deep
      #pragma unroll
      for (int nt = 0; nt < 8; ++nt) {
        int n = 8 * w + nt;
        const bf16x8* w1p = W1P + n * 6 * 64 + lane;
        bf16x8 f0 = w1p[0 * 64];
        bf16x8 f1 = w1p[1 * 64];
        bf16x8 f2 = w1p[2 * 64];
        bf16x8 f3 = w1p[3 * 64];
        bf16x8 f4 = w1p[4 * 64];
        bf16x8 f5 = w1p[5 * 64];
        f32x4 aa = {0,0,0,0}, ab = {0,0,0,0};
        aa = __builtin_amdgcn_mfma_f32_16x16x32_bf16(za[0], f0, aa, 0, 0, 0);
        ab = __builtin_amdgcn_mfma_f32_16x16x32_bf16(za[1], f1, ab, 0, 0, 0);
        aa = __builtin_amdgcn_mfma_f32_16x16x32_bf16(za[2], f2, aa, 0, 0, 0);
        ab = __builtin_amdgcn_mfma_f32_16x16x32_bf16(za[3], f3, ab, 0, 0, 0);
        aa = __builtin_amdgcn_mfma_f32_16x16x32_bf16(za[4], f4, aa, 0, 0, 0);
        ab = __builtin_amdgcn_mfma_f32_16x16x32_bf16(za[5], f5, ab, 0, 0, 0);
        float bias = b1r[nt];
        #pragma unroll
        for (int q = 0; q < 4; ++q) {
          float hv = tanh_fast(aa[q] + ab[q] + bias);
          hs[4 * g + q][16 * n + r16] = f2bf(hv);
        }
      }
      if (e == 0 && w == 0) {
        // y_t = x C^T + u D^T, reuses z fragments (z k 0..127 = x -> C, 128..191 = u -> D)
        f32x4 ay = {0,0,0,0};
        #pragma unroll
        for (int ks = 0; ks < 4; ++ks)
          ay = __builtin_amdgcn_mfma_f32_16x16x32_bf16(za[ks], CP[ks * 64 + lane], ay, 0, 0, 0);
        ay = __builtin_amdgcn_mfma_f32_16x16x32_bf16(za[4], DP[lane],      ay, 0, 0, 0);
        ay = __builtin_amdgcn_mfma_f32_16x16x32_bf16(za[5], DP[64 + lane], ay, 0, 0, 0);
        #pragma unroll
        for (int q = 0; q < 4; ++q)
          Yout[((b0 + 4 * g + q) * kT + t) * kNY + r16] = ay[q];
      }
      __syncthreads();

      // ---- matmul2: k = h @ W2^T + b2; wave w owns NX cols [16w, 16w+16)
      // fully unrolled, 4 accumulators, 32 independent W2 loads + 32 LDS reads
      f32x4 ka = {0,0,0,0}, kb = {0,0,0,0}, kc = {0,0,0,0}, kd = {0,0,0,0};
      const bf16x8* w2p = W2P + w * 32 * 64 + lane;
      #pragma unroll
      for (int ks = 0; ks < 32; ks += 4) {
        bf16x8 h0 = *(const bf16x8*)&hs[r16][8 * g + 32 * ks];
        bf16x8 h1 = *(const bf16x8*)&hs[r16][8 * g + 32 * (ks + 1)];
        bf16x8 h2 = *(const bf16x8*)&hs[r16][8 * g + 32 * (ks + 2)];
        bf16x8 h3 = *(const bf16x8*)&hs[r16][8 * g + 32 * (ks + 3)];
        bf16x8 g0 = w2p[ks * 64];
        bf16x8 g1 = w2p[(ks + 1) * 64];
        bf16x8 g2 = w2p[(ks + 2) * 64];
        bf16x8 g3 = w2p[(ks + 3) * 64];
        ka = __builtin_amdgcn_mfma_f32_16x16x32_bf16(h0, g0, ka, 0, 0, 0);
        kb = __builtin_amdgcn_mfma_f32_16x16x32_bf16(h1, g1, kb, 0, 0, 0);
        kc = __builtin_amdgcn_mfma_f32_16x16x32_bf16(h2, g2, kc, 0, 0, 0);
        kd = __builtin_amdgcn_mfma_f32_16x16x32_bf16(h3, g3, kd, 0, 0, 0);
      }
      f32x4 kv = (ka + kb) + (kc + kd);
      #pragma unroll
      for (int q = 0; q < 4; ++q) kv[q] += b2reg;

      if      (e == 0) k1r = kv;
      else if (e == 1) k2r = kv;
      else if (e == 2) k3r = kv;
      else if (e == 3) k4r = kv;
      else if (e == 4) k5r = kv;

      if (e < 5) {
        // z for next stage: x + sum(CT[e][j] * k_j)  (unused k's are 0-coef, stale-but-finite)
        float c1 = CTc[e][0], c2 = CTc[e][1], c3 = CTc[e][2], c4 = CTc[e][3], c5 = CTc[e][4];
        #pragma unroll
        for (int q = 0; q < 4; ++q) {
          float xt = xreg[q] + c1 * k1r[q] + c2 * k2r[q] + c3 * k3r[q] + c4 * k4r[q] + c5 * k5r[q];
          zs[4 * g + q][colw] = f2bf(xt);
        }
      } else {
        // x_{t+1} = x_t + dt * (16/135 k1 + 6656/12825 k3 + 28561/56430 k4 - 9/50 k5 + 2/55 k6)
        #pragma unroll
        for (int q = 0; q < 4; ++q) {
          float xn = xreg[q] + (D1 * k1r[q] + D3 * k3r[q] + D4 * k4r[q] + D5 * k5r[q] + D6 * kv[q]);
          xreg[q] = xn;
          xs[4 * g + q][colw] = xn;
          zs[4 * g + q][colw] = f2bf(xn);
        }
      }
      __syncthreads();
    }
  }
}

extern "C" void kernel_launch(void* const* d_in, const int* in_sizes, int n_in,
                              void* d_out, int out_size, void* d_ws, size_t ws_size,
                              hipStream_t stream) {
  const float* u  = (const float*)d_in[0];
  const float* x0 = (const float*)d_in[1];
  const float* W1 = (const float*)d_in[2];
  const float* b1 = (const float*)d_in[3];
  const float* W2 = (const float*)d_in[4];
  const float* b2 = (const float*)d_in[5];
  const float* C  = (const float*)d_in[6];
  const float* D  = (const float*)d_in[7];

  unsigned short* wp = (unsigned short*)d_ws;
  float* Xout = (float*)d_out;
  float* Yout = Xout + (size_t)512 * 256 * 128;

  hipLaunchKernelGGL(prepack_kernel, dim3((kPackTotal + 255) / 256), dim3(256), 0, stream,
                     W1, W2, C, D, wp);
  hipLaunchKernelGGL(rk45_kernel, dim3(32), dim3(512), 0, stream,
                     u, x0, b1, b2, (const unsigned short*)wp, Xout, Yout);
}

// Round 5
// 11595.937 us; speedup vs baseline: 1.9935x; 1.4064x over previous
//
#include <hip/hip_runtime.h>

typedef short bf16x8 __attribute__((ext_vector_type(8)));
typedef float f32x4 __attribute__((ext_vector_type(4)));

static constexpr int kT  = 256;
static constexpr int kNU = 64;
static constexpr int kNX = 128;
static constexpr int kNY = 16;
static constexpr int kBT = 16;   // batch rows per block

// packed weight region sizes (elements)
static constexpr int kW1P = 64 * 6 * 64 * 8;   // 196608
static constexpr int kW2P = 8 * 32 * 64 * 8;   // 131072
static constexpr int kCP  = 4 * 64 * 8;        // 2048
static constexpr int kDP  = 2 * 64 * 8;        // 1024
static constexpr int kPackTotal = kW1P + kW2P + kCP + kDP; // 330752

__device__ __forceinline__ unsigned short f2bf(float f) {
  union { float f; unsigned int u; } v; v.f = f;
  unsigned int r = v.u + 0x7fffu + ((v.u >> 16) & 1u);   // RNE to bf16
  return (unsigned short)(r >> 16);
}

// Pack W1/W2/C/D (fp32) into bf16 MFMA B-fragment order:
// frag index (n, ks, lane, j) holds W[16n + (lane&15)][32ks + 8*(lane>>4) + j]
__global__ __launch_bounds__(256)
void prepack_kernel(const float* __restrict__ W1, const float* __restrict__ W2,
                    const float* __restrict__ C, const float* __restrict__ D,
                    unsigned short* __restrict__ wp) {
  int i = blockIdx.x * 256 + threadIdx.x;
  if (i >= kPackTotal) return;
  float v;
  if (i < kW1P) {
    int j = i & 7, l = (i >> 3) & 63, t = i >> 9;
    int ks = t % 6, n = t / 6;
    v = W1[(16 * n + (l & 15)) * 192 + 32 * ks + 8 * (l >> 4) + j];
  } else if (i < kW1P + kW2P) {
    int k = i - kW1P;
    int j = k & 7, l = (k >> 3) & 63, t = k >> 9;
    int ks = t & 31, n = t >> 5;
    v = W2[(16 * n + (l & 15)) * 1024 + 32 * ks + 8 * (l >> 4) + j];
  } else if (i < kW1P + kW2P + kCP) {
    int k = i - (kW1P + kW2P);
    int j = k & 7, l = (k >> 3) & 63, ks = k >> 9;
    v = C[(l & 15) * 128 + 32 * ks + 8 * (l >> 4) + j];
  } else {
    int k = i - (kW1P + kW2P + kCP);
    int j = k & 7, l = (k >> 3) & 63, ks = k >> 9;
    v = D[(l & 15) * 64 + 32 * ks + 8 * (l >> 4) + j];
  }
  wp[i] = f2bf(v);
}

// RK45 stage-combination coefficients (dt folded in), row e = coeffs for z of stage e+2
__constant__ float CTc[5][5] = {
  {(float)(0.01 / 4.0), 0.f, 0.f, 0.f, 0.f},
  {(float)(0.01 * 3.0 / 32.0), (float)(0.01 * 9.0 / 32.0), 0.f, 0.f, 0.f},
  {(float)(0.01 * 1932.0 / 2197.0), (float)(-0.01 * 7200.0 / 2197.0), (float)(0.01 * 7296.0 / 2197.0), 0.f, 0.f},
  {(float)(0.01 * 439.0 / 216.0), (float)(-0.01 * 8.0), (float)(0.01 * 3680.0 / 513.0), (float)(-0.01 * 845.0 / 4104.0), 0.f},
  {(float)(-0.01 * 8.0 / 27.0), (float)(0.01 * 2.0), (float)(-0.01 * 3544.0 / 2565.0), (float)(0.01 * 1859.0 / 4104.0), (float)(-0.01 * 11.0 / 40.0)}
};

// tanh(x) = 1 - 2/(exp2(2x*log2 e)+1)
__device__ __forceinline__ float tanh_fast(float x) {
  float t = exp2f(x * 2.8853900817779268f);
  return 1.0f - 2.0f * __builtin_amdgcn_rcpf(t + 1.0f);
}

// async global->LDS, 16B per lane. lds base must be wave-uniform; global addr is per-lane.
__device__ __forceinline__ void gll16(const void* g, void* l) {
  __builtin_amdgcn_global_load_lds((const __attribute__((address_space(1))) unsigned int*)g,
                                   (__attribute__((address_space(3))) unsigned int*)l, 16, 0, 0);
}

// One block = 16 batch rows, 8 waves. Whole T-loop inside the kernel.
// Weights stream through a 96KB LDS double-buffer via global_load_lds,
// prefetched 2 chunks deep with counted vmcnt (never drained mid-phase).
__global__ __launch_bounds__(512, 2)
void rk45_kernel(const float* __restrict__ u, const float* __restrict__ x0,
                 const float* __restrict__ b1g, const float* __restrict__ b2g,
                 const unsigned short* __restrict__ wp,
                 float* __restrict__ Xout, float* __restrict__ Yout) {
  __shared__ __align__(16) unsigned short zs[16][232];   // z = [x | u] bf16
  __shared__ __align__(16) unsigned short hs[16][1048];  // h bf16 (16 x 1024)
  __shared__ __align__(16) float xs[16][132];            // master state fp32
  __shared__ __align__(16) short wbuf[2][8][6][512];     // weight chunk double-buffer (96KB)

  const int tid  = threadIdx.x;
  const int lane = tid & 63;
  const int w    = tid >> 6;     // wave 0..7
  const int r16  = lane & 15;
  const int g    = lane >> 4;    // 0..3
  const int b0   = blockIdx.x * kBT;
  const int colw = 16 * w + r16;

  const char* wpb = (const char*)wp;   // byte base of packed weights

  // ---- chunk issue helpers (all addresses stage-invariant) ----
  // W1 chunk nt (nt=0..7): 6 frags (ks 0..5) for NH tile n=8w+nt -> wbuf[b][w][0..5]
  auto issueW1 = [&](int nt, int b) {
    const char* gb = wpb + (size_t)(8 * w + nt) * 6 * 1024 + lane * 16;
    #pragma unroll
    for (int ks = 0; ks < 6; ++ks)
      gll16(gb + ks * 1024, &wbuf[b][w][ks][0]);
  };
  // W2 chunk c (c=0..7): 4 frags (ks 4c..4c+3) -> wbuf[b][w][0..3]
  auto issueW2 = [&](int c, int b) {
    const char* gb = wpb + (size_t)kW1P * 2 + (size_t)(w * 32 + 4 * c) * 1024 + lane * 16;
    #pragma unroll
    for (int s = 0; s < 4; ++s)
      gll16(gb + s * 1024, &wbuf[b][w][s][0]);
  };

  // ---- persistent small registers ----
  float b1r[8];
  #pragma unroll
  for (int nt = 0; nt < 8; ++nt)
    b1r[nt] = b1g[128 * w + 16 * nt + r16];
  const float b2reg = b2g[colw];

  const bf16x8* CP = (const bf16x8*)(wp + kW1P + kW2P);
  const bf16x8* DP = (const bf16x8*)(wp + kW1P + kW2P + kCP);
  bf16x8 cpr[4], dpr[2];
  #pragma unroll
  for (int ks = 0; ks < 4; ++ks) cpr[ks] = CP[ks * 64 + lane];
  dpr[0] = DP[lane];
  dpr[1] = DP[64 + lane];

  float xreg[4];
  f32x4 k1r = {0,0,0,0}, k2r = {0,0,0,0}, k3r = {0,0,0,0}, k4r = {0,0,0,0}, k5r = {0,0,0,0};

  #pragma unroll
  for (int q = 0; q < 4; ++q) {
    int row = 4 * g + q;
    float xv = x0[(b0 + row) * kNX + colw];
    xreg[q] = xv;
    xs[row][colw] = xv;
    zs[row][colw] = f2bf(xv);
  }

  // prefetch W1 chunks 0,1 for the first stage; init barrier drains them into LDS
  issueW1(0, 0);
  issueW1(1, 1);
  __syncthreads();

  const float D1 = (float)(0.01 * 16.0 / 135.0);
  const float D3 = (float)(0.01 * 6656.0 / 12825.0);
  const float D4 = (float)(0.01 * 28561.0 / 56430.0);
  const float D5 = (float)(-0.01 * 9.0 / 50.0);
  const float D6 = (float)(0.01 * 2.0 / 55.0);

  #pragma unroll 1
  for (int t = 0; t < kT; ++t) {
    // ---- stage A: write X[t] from xs (coalesced), load+commit u_t
    {
      int base = tid * 4, row = base >> 7, col = base & 127;
      float4 xv = *(const float4*)&xs[row][col];
      *(float4*)&Xout[((b0 + row) * kT + t) * kNX + col] = xv;
      int urow = tid >> 5, ucol = (tid & 31) * 2;
      float2 uv = *(const float2*)&u[((b0 + urow) * kT + t) * kNU + ucol];
      zs[urow][kNX + ucol]     = f2bf(uv.x);
      zs[urow][kNX + ucol + 1] = f2bf(uv.y);
    }
    __syncthreads();   // drains nothing pending except stageA ops; W1 c0,c1 already in LDS

    #pragma unroll 1
    for (int e = 0; e < 6; ++e) {
      // ---- matmul1: h = tanh(z @ W1^T + b1); wave w owns NH slice [128w, 128w+128)
      bf16x8 za[6];
      #pragma unroll
      for (int ks = 0; ks < 6; ++ks)
        za[ks] = *(const bf16x8*)&zs[r16][8 * g + 32 * ks];

      #pragma unroll
      for (int nt = 0; nt < 8; ++nt) {
        // wait for chunk nt (2-deep pipeline, counted waits, never 0)
        if (nt >= 2 && nt <= 6) { asm volatile("s_waitcnt vmcnt(6)" ::: "memory"); }
        else if (nt == 7)       { asm volatile("s_waitcnt vmcnt(4)" ::: "memory"); }
        const int b = nt & 1;
        bf16x8 f0 = *(const bf16x8*)&wbuf[b][w][0][lane * 8];
        bf16x8 f1 = *(const bf16x8*)&wbuf[b][w][1][lane * 8];
        bf16x8 f2 = *(const bf16x8*)&wbuf[b][w][2][lane * 8];
        bf16x8 f3 = *(const bf16x8*)&wbuf[b][w][3][lane * 8];
        bf16x8 f4 = *(const bf16x8*)&wbuf[b][w][4][lane * 8];
        bf16x8 f5 = *(const bf16x8*)&wbuf[b][w][5][lane * 8];
        // reads must land before the next DMA overwrites this buffer
        asm volatile("s_waitcnt lgkmcnt(0)" ::: "memory");
        if (nt <= 5)      issueW1(nt + 2, b);
        else if (nt == 6) issueW2(0, 0);
        else              issueW2(1, 1);

        f32x4 aa = {0,0,0,0}, ab = {0,0,0,0};
        aa = __builtin_amdgcn_mfma_f32_16x16x32_bf16(za[0], f0, aa, 0, 0, 0);
        ab = __builtin_amdgcn_mfma_f32_16x16x32_bf16(za[1], f1, ab, 0, 0, 0);
        aa = __builtin_amdgcn_mfma_f32_16x16x32_bf16(za[2], f2, aa, 0, 0, 0);
        ab = __builtin_amdgcn_mfma_f32_16x16x32_bf16(za[3], f3, ab, 0, 0, 0);
        aa = __builtin_amdgcn_mfma_f32_16x16x32_bf16(za[4], f4, aa, 0, 0, 0);
        ab = __builtin_amdgcn_mfma_f32_16x16x32_bf16(za[5], f5, ab, 0, 0, 0);

        float bias = b1r[nt];
        int n = 8 * w + nt;
        #pragma unroll
        for (int q = 0; q < 4; ++q) {
          float hv = tanh_fast(aa[q] + ab[q] + bias);
          hs[4 * g + q][16 * n + r16] = f2bf(hv);
        }
      }

      if (e == 0 && w == 0) {
        // y_t = x C^T + u D^T from register-resident C/D fragments
        f32x4 ay = {0,0,0,0};
        #pragma unroll
        for (int ks = 0; ks < 4; ++ks)
          ay = __builtin_amdgcn_mfma_f32_16x16x32_bf16(za[ks], cpr[ks], ay, 0, 0, 0);
        ay = __builtin_amdgcn_mfma_f32_16x16x32_bf16(za[4], dpr[0], ay, 0, 0, 0);
        ay = __builtin_amdgcn_mfma_f32_16x16x32_bf16(za[5], dpr[1], ay, 0, 0, 0);
        #pragma unroll
        for (int q = 0; q < 4; ++q)
          Yout[((b0 + 4 * g + q) * kT + t) * kNY + r16] = ay[q];
      }
      __syncthreads();   // hs ready; drains W2 c0,c1 into LDS

      // ---- matmul2: k = h @ W2^T + b2; wave w owns NX cols [16w, 16w+16)
      f32x4 ka = {0,0,0,0}, kb = {0,0,0,0};
      #pragma unroll
      for (int c = 0; c < 8; ++c) {
        if (c >= 2 && c <= 6) { asm volatile("s_waitcnt vmcnt(4)" ::: "memory"); }
        else if (c == 7)      { asm volatile("s_waitcnt vmcnt(6)" ::: "memory"); }
        const int b = c & 1;
        bf16x8 g0 = *(const bf16x8*)&wbuf[b][w][0][lane * 8];
        bf16x8 g1 = *(const bf16x8*)&wbuf[b][w][1][lane * 8];
        bf16x8 g2 = *(const bf16x8*)&wbuf[b][w][2][lane * 8];
        bf16x8 g3 = *(const bf16x8*)&wbuf[b][w][3][lane * 8];
        bf16x8 h0 = *(const bf16x8*)&hs[r16][8 * g + 32 * (4 * c + 0)];
        bf16x8 h1 = *(const bf16x8*)&hs[r16][8 * g + 32 * (4 * c + 1)];
        bf16x8 h2 = *(const bf16x8*)&hs[r16][8 * g + 32 * (4 * c + 2)];
        bf16x8 h3 = *(const bf16x8*)&hs[r16][8 * g + 32 * (4 * c + 3)];
        asm volatile("s_waitcnt lgkmcnt(0)" ::: "memory");
        if (c <= 5)      issueW2(c + 2, b);
        else if (c == 6) issueW1(0, 0);   // prefetch next stage's W1 c0
        else             issueW1(1, 1);   // and c1

        ka = __builtin_amdgcn_mfma_f32_16x16x32_bf16(h0, g0, ka, 0, 0, 0);
        kb = __builtin_amdgcn_mfma_f32_16x16x32_bf16(h1, g1, kb, 0, 0, 0);
        ka = __builtin_amdgcn_mfma_f32_16x16x32_bf16(h2, g2, ka, 0, 0, 0);
        kb = __builtin_amdgcn_mfma_f32_16x16x32_bf16(h3, g3, kb, 0, 0, 0);
      }
      f32x4 kv = ka + kb;
      #pragma unroll
      for (int q = 0; q < 4; ++q) kv[q] += b2reg;

      if      (e == 0) k1r = kv;
      else if (e == 1) k2r = kv;
      else if (e == 2) k3r = kv;
      else if (e == 3) k4r = kv;
      else if (e == 4) k5r = kv;

      if (e < 5) {
        float c1 = CTc[e][0], c2 = CTc[e][1], c3 = CTc[e][2], c4 = CTc[e][3], c5 = CTc[e][4];
        #pragma unroll
        for (int q = 0; q < 4; ++q) {
          float xt = xreg[q] + c1 * k1r[q] + c2 * k2r[q] + c3 * k3r[q] + c4 * k4r[q] + c5 * k5r[q];
          zs[4 * g + q][colw] = f2bf(xt);
        }
      } else {
        #pragma unroll
        for (int q = 0; q < 4; ++q) {
          float xn = xreg[q] + (D1 * k1r[q] + D3 * k3r[q] + D4 * k4r[q] + D5 * k5r[q] + D6 * kv[q]);
          xreg[q] = xn;
          xs[4 * g + q][colw] = xn;
          zs[4 * g + q][colw] = f2bf(xn);
        }
      }
      __syncthreads();   // zs ready; drains next stage's W1 c0,c1 into LDS
    }
  }
}

extern "C" void kernel_launch(void* const* d_in, const int* in_sizes, int n_in,
                              void* d_out, int out_size, void* d_ws, size_t ws_size,
                              hipStream_t stream) {
  const float* u  = (const float*)d_in[0];
  const float* x0 = (const float*)d_in[1];
  const float* W1 = (const float*)d_in[2];
  const float* b1 = (const float*)d_in[3];
  const float* W2 = (const float*)d_in[4];
  const float* b2 = (const float*)d_in[5];
  const float* C  = (const float*)d_in[6];
  const float* D  = (const float*)d_in[7];

  unsigned short* wp = (unsigned short*)d_ws;
  float* Xout = (float*)d_out;
  float* Yout = Xout + (size_t)512 * 256 * 128;

  hipLaunchKernelGGL(prepack_kernel, dim3((kPackTotal + 255) / 256), dim3(256), 0, stream,
                     W1, W2, C, D, wp);
  hipLaunchKernelGGL(rk45_kernel, dim3(32), dim3(512), 0, stream,
                     u, x0, b1, b2, (const unsigned short*)wp, Xout, Yout);
}